// Round 8
// baseline (377.795 us; speedup 1.0000x reference)
//
#include <hip/hip_runtime.h>

// MultiheadAttention: B=4, S=2048, D_MODEL=1024, H=16, D_K=64, fp32 in/out.
// Pipeline (bf16 MFMA, fp32 accum):
//   1. transpose4: W[K][N] f32 -> Wt[N][K] bf16 (all 4 weights, one launch, ~6us)
//   2. gemm_qkv: Q,K,V projections reading q/k/v F32 DIRECTLY (fused convert:
//      A reg-staged 8x loadx4 -> pack_bf -> swizzled ds_write_b64, T14 split;
//      B bf16 via async GLD, 3 buffers; counted vmcnt(2) schedule, 1 barrier/tile).
//      Eliminates the 144 MB f32->bf16 intermediate round-trip entirely.
//      V epilogue permutation = swap kv bits 2<->3 (matches 32x32 PV B-fragment).
//   3. attn: best-measured (83.6us): 32x32x16 MFMA, 32 q/wave, grid (64,16),
//      GLD staging with pre-swizzled source, 2-buffer K/V, one barrier/tile.
//   4. gemm_out: 3-buffer GLD core, 256 blocks = exactly 1 CU round.

#define DM 1024
#define SQL 2048

typedef __attribute__((ext_vector_type(4))) float floatx4;
typedef __attribute__((ext_vector_type(16))) float floatx16;
typedef __attribute__((ext_vector_type(8))) __bf16 bf16x8;
typedef __attribute__((ext_vector_type(4))) __bf16 bf16x4;

// swizzled LDS address (halves): 64-half rows, 8-half chunks, chunk XOR row&7
#define SW(row, chunk) (((row) << 6) + ((((chunk) ^ ((row) & 7))) << 3))

// async 16B global->LDS copy; lds base must be wave-uniform (lane writes base+lane*16B)
#define GLD(gaddr, laddr)                                                              \
  __builtin_amdgcn_global_load_lds(                                                    \
      (const __attribute__((address_space(1))) unsigned int*)(gaddr),                  \
      (__attribute__((address_space(3))) unsigned int*)(laddr), 16, 0, 0)

__device__ __forceinline__ unsigned short f2bf(float f) {
  unsigned int u = __float_as_uint(f);
  u += 0x7fffu + ((u >> 16) & 1u);   // RNE
  return (unsigned short)(u >> 16);
}

// pack two f32 -> bf16 pair via v_perm (round-half-up); result: lo in low half
__device__ __forceinline__ unsigned int pack_bf(float lo, float hi) {
  unsigned int a = __float_as_uint(lo) + 0x8000u;
  unsigned int b = __float_as_uint(hi) + 0x8000u;
  return __builtin_amdgcn_perm(b, a, 0x07060302u);  // {b.hi16, a.hi16}
}

// ---------------- all-4 weight transpose: W[1024][1024] f32 -> Wt[1024][1024] bf16
__global__ __launch_bounds__(256) void transpose4_kernel(
    const float* __restrict__ w0, const float* __restrict__ w1,
    const float* __restrict__ w2, const float* __restrict__ w3,
    unsigned short* __restrict__ t0, unsigned short* __restrict__ t1,
    unsigned short* __restrict__ t2, unsigned short* __restrict__ t3) {
  __shared__ unsigned short t[64][65];
  int z = blockIdx.z;
  const float* W = (z == 0) ? w0 : (z == 1) ? w1 : (z == 2) ? w2 : w3;
  unsigned short* Wt = (z == 0) ? t0 : (z == 1) ? t1 : (z == 2) ? t2 : t3;
  int tid = threadIdx.x;
  int n0 = blockIdx.x * 64, k0 = blockIdx.y * 64;
  for (int u = 0; u < 16; u++) {
    int idx = u * 256 + tid;
    int k = idx >> 6, n = idx & 63;
    t[k][n] = f2bf(W[(size_t)(k0 + k) * DM + n0 + n]);
  }
  __syncthreads();
  for (int u = 0; u < 16; u++) {
    int idx = u * 256 + tid;
    int n = idx >> 6, k = idx & 63;
    Wt[(size_t)(n0 + n) * DM + k0 + k] = t[k][n];
  }
}

// ---------------- QKV GEMM with FUSED f32->bf16 convert on the A path.
// C[256x128] tile, K=1024, BK=64. 8 waves as 4M x 2N. A: f32 source, reg-staged
// (8x loadx4 issued at tile top, pack_bf + swizzled ds_write_b64 at tile end into
// the 2-buffer A LDS not read this tile). B: bf16 weights via async GLD, 3 buffers.
// Counted schedule per tile t: issue [A(t+1) x8, B(t+2) x2]; compute 2 phases;
// s_waitcnt vmcnt(2) (B(t+1)/A(t+1) older -> landed; only B(t+2) in flight);
// cvt+write A(t+1); lgkmcnt(0)+barrier. Race-free: A(t+1) written to abuf^(t&1)
// whose readers (tile t-1) finished before this tile's top barrier; B(t+2) lands
// in bbuf (t+2)%3 whose readers (tile t-1) likewise finished.
__global__ __launch_bounds__(512, 2) void gemm_qkv_kernel(
    const float* __restrict__ qf32, const float* __restrict__ kf32,
    const float* __restrict__ vf32, const unsigned short* __restrict__ wqt,
    const unsigned short* __restrict__ wkt, const unsigned short* __restrict__ wvt,
    const float* __restrict__ bq, const float* __restrict__ bk,
    const float* __restrict__ bv, unsigned short* __restrict__ Qb,
    unsigned short* __restrict__ Kb, unsigned short* __restrict__ VtOut,
    float qscale) {
  __shared__ unsigned short lds_a[2 * 256 * 64];  // 64 KiB, 2 buffers
  __shared__ unsigned short lds_b[3 * 128 * 64];  // 48 KiB, 3 buffers

  // bijective XCD swizzle: 768 blocks, 96 consecutive logical tiles per XCD
  int lin = blockIdx.x + (blockIdx.y << 3) + (blockIdx.z << 8);
  int swz = (lin & 7) * 96 + (lin >> 3);
  int z = swz >> 8, rem = swz & 255;
  int m0 = (rem >> 3) << 8;  // mTile*256
  int n0 = (rem & 7) << 7;   // nTile*128

  const float* A = (z == 0) ? qf32 : (z == 1) ? kf32 : vf32;
  const unsigned short* Bt = (z == 0) ? wqt : (z == 1) ? wkt : wvt;
  const float* bias = (z == 0) ? bq : (z == 1) ? bk : bv;

  int tid = threadIdx.x;
  int wave = tid >> 6, lane = tid & 63;
  int quad = lane >> 4, c16 = lane & 15;
  int wm = wave >> 1, wn = wave & 1;
  int r8 = lane >> 3, l8 = lane & 7;
  int xch = (l8 ^ r8) << 3;  // pre-swizzled B source chunk offset (halves)

  int r7 = c16 & 7;
  int aoff0 = ((wm * 64 + c16) << 6) + ((quad ^ r7) << 3);
  int aoff1 = ((wm * 64 + c16) << 6) + (((4 + quad) ^ r7) << 3);
  int boff0 = ((wn * 64 + c16) << 6) + ((quad ^ r7) << 3);
  int boff1 = ((wn * 64 + c16) << 6) + (((4 + quad) ^ r7) << 3);

  // ---- A f32 staging geometry: per load u (0..7): row = wave*32 + u*4 + (lane>>4),
  // f32 cols = (lane&15)*4. LDS write: halves h0=(lane&15)*4 of that row, swizzled.
  int arow = lane >> 4;                 // 0..3
  int acol4 = (c16) * 4;                // f32 col within BK
  const float* agp = &A[(size_t)(m0 + wave * 32 + arow) * DM + acol4];
  int cw = c16 >> 1;                    // element chunk of the b64 write
  int awbase = ((wave * 32 + arow) << 6) + ((lane & 1) << 2);

  // ---- B staging (async GLD, bf16)
  int bq_ = wave * 2;
#define STG_B(bufi, kt, u) \
  GLD(&Bt[(size_t)(n0 + (bq_ + (u)) * 8 + r8) * DM + (kt) + xch], \
      lds_b + (bufi) * 8192 + (bq_ + (u)) * 512)

// issue 8 A loads for K-tile TT into regs AR
#define A_ISSUE(AR, TT)                                                                \
  _Pragma("unroll") for (int u_ = 0; u_ < 8; u_++)                                     \
      AR[u_] = *(const float4*)(agp + (size_t)(u_ * 4) * DM + ((TT) << 6));
// convert + swizzled ds_write of regs AR into A buffer BUFI
#define A_WRITE(AR, BUFI)                                                              \
  _Pragma("unroll") for (int u_ = 0; u_ < 8; u_++) {                                   \
    int r7u_ = (arow + ((u_ & 1) << 2)) & 7;                                           \
    uint2 pw_;                                                                         \
    pw_.x = pack_bf(AR[u_].x, AR[u_].y);                                               \
    pw_.y = pack_bf(AR[u_].z, AR[u_].w);                                               \
    *(uint2*)&lds_a[(BUFI) * 16384 + awbase + u_ * 256 + ((cw ^ r7u_) << 3)] = pw_;    \
  }

  const floatx4 fz = {0.f, 0.f, 0.f, 0.f};
  floatx4 acc[4][4];
#pragma unroll
  for (int i = 0; i < 4; i++)
#pragma unroll
    for (int j = 0; j < 4; j++) acc[i][j] = fz;

  // ---- prologue: A(0) loads; B(0),B(1) GLDs; wait A(0); write A(0)->abuf0;
  // wait B(0); barrier.
  float4 areg[8];
  A_ISSUE(areg, 0);
  STG_B(0, 0, 0); STG_B(0, 0, 1);
  STG_B(1, 64, 0); STG_B(1, 64, 1);
  asm volatile("s_waitcnt vmcnt(4)" ::: "memory");
  A_WRITE(areg, 0);
  asm volatile("s_waitcnt vmcnt(2) lgkmcnt(0)" ::: "memory");
  __builtin_amdgcn_s_barrier();

#pragma unroll 1
  for (int t = 0; t < 16; ++t) {
    // issue next A / next-next B
    if (t + 1 < 16) A_ISSUE(areg, t + 1);
    if (t + 2 < 16) {
      int bb = (t + 2) % 3;
      STG_B(bb, (t + 2) << 6, 0);
      STG_B(bb, (t + 2) << 6, 1);
    }

    const unsigned short* la = lds_a + (t & 1) * 16384;
    const unsigned short* lb = lds_b + (t % 3) * 8192;

    // ---- phase ks=0: 8 ds_reads + 16 MFMA
    {
      bf16x8 a0 = *(const bf16x8*)&la[aoff0];
      bf16x8 a1 = *(const bf16x8*)&la[aoff0 + 1024];
      bf16x8 a2 = *(const bf16x8*)&la[aoff0 + 2048];
      bf16x8 a3 = *(const bf16x8*)&la[aoff0 + 3072];
      bf16x8 b0 = *(const bf16x8*)&lb[boff0];
      bf16x8 b1 = *(const bf16x8*)&lb[boff0 + 1024];
      bf16x8 b2 = *(const bf16x8*)&lb[boff0 + 2048];
      bf16x8 b3 = *(const bf16x8*)&lb[boff0 + 3072];
      __builtin_amdgcn_s_setprio(1);
      acc[0][0] = __builtin_amdgcn_mfma_f32_16x16x32_bf16(a0, b0, acc[0][0], 0, 0, 0);
      acc[0][1] = __builtin_amdgcn_mfma_f32_16x16x32_bf16(a0, b1, acc[0][1], 0, 0, 0);
      acc[0][2] = __builtin_amdgcn_mfma_f32_16x16x32_bf16(a0, b2, acc[0][2], 0, 0, 0);
      acc[0][3] = __builtin_amdgcn_mfma_f32_16x16x32_bf16(a0, b3, acc[0][3], 0, 0, 0);
      acc[1][0] = __builtin_amdgcn_mfma_f32_16x16x32_bf16(a1, b0, acc[1][0], 0, 0, 0);
      acc[1][1] = __builtin_amdgcn_mfma_f32_16x16x32_bf16(a1, b1, acc[1][1], 0, 0, 0);
      acc[1][2] = __builtin_amdgcn_mfma_f32_16x16x32_bf16(a1, b2, acc[1][2], 0, 0, 0);
      acc[1][3] = __builtin_amdgcn_mfma_f32_16x16x32_bf16(a1, b3, acc[1][3], 0, 0, 0);
      acc[2][0] = __builtin_amdgcn_mfma_f32_16x16x32_bf16(a2, b0, acc[2][0], 0, 0, 0);
      acc[2][1] = __builtin_amdgcn_mfma_f32_16x16x32_bf16(a2, b1, acc[2][1], 0, 0, 0);
      acc[2][2] = __builtin_amdgcn_mfma_f32_16x16x32_bf16(a2, b2, acc[2][2], 0, 0, 0);
      acc[2][3] = __builtin_amdgcn_mfma_f32_16x16x32_bf16(a2, b3, acc[2][3], 0, 0, 0);
      acc[3][0] = __builtin_amdgcn_mfma_f32_16x16x32_bf16(a3, b0, acc[3][0], 0, 0, 0);
      acc[3][1] = __builtin_amdgcn_mfma_f32_16x16x32_bf16(a3, b1, acc[3][1], 0, 0, 0);
      acc[3][2] = __builtin_amdgcn_mfma_f32_16x16x32_bf16(a3, b2, acc[3][2], 0, 0, 0);
      acc[3][3] = __builtin_amdgcn_mfma_f32_16x16x32_bf16(a3, b3, acc[3][3], 0, 0, 0);
      __builtin_amdgcn_s_setprio(0);
    }
    // ---- phase ks=1
    {
      bf16x8 a0 = *(const bf16x8*)&la[aoff1];
      bf16x8 a1 = *(const bf16x8*)&la[aoff1 + 1024];
      bf16x8 a2 = *(const bf16x8*)&la[aoff1 + 2048];
      bf16x8 a3 = *(const bf16x8*)&la[aoff1 + 3072];
      bf16x8 b0 = *(const bf16x8*)&lb[boff1];
      bf16x8 b1 = *(const bf16x8*)&lb[boff1 + 1024];
      bf16x8 b2 = *(const bf16x8*)&lb[boff1 + 2048];
      bf16x8 b3 = *(const bf16x8*)&lb[boff1 + 3072];
      __builtin_amdgcn_s_setprio(1);
      acc[0][0] = __builtin_amdgcn_mfma_f32_16x16x32_bf16(a0, b0, acc[0][0], 0, 0, 0);
      acc[0][1] = __builtin_amdgcn_mfma_f32_16x16x32_bf16(a0, b1, acc[0][1], 0, 0, 0);
      acc[0][2] = __builtin_amdgcn_mfma_f32_16x16x32_bf16(a0, b2, acc[0][2], 0, 0, 0);
      acc[0][3] = __builtin_amdgcn_mfma_f32_16x16x32_bf16(a0, b3, acc[0][3], 0, 0, 0);
      acc[1][0] = __builtin_amdgcn_mfma_f32_16x16x32_bf16(a1, b0, acc[1][0], 0, 0, 0);
      acc[1][1] = __builtin_amdgcn_mfma_f32_16x16x32_bf16(a1, b1, acc[1][1], 0, 0, 0);
      acc[1][2] = __builtin_amdgcn_mfma_f32_16x16x32_bf16(a1, b2, acc[1][2], 0, 0, 0);
      acc[1][3] = __builtin_amdgcn_mfma_f32_16x16x32_bf16(a1, b3, acc[1][3], 0, 0, 0);
      acc[2][0] = __builtin_amdgcn_mfma_f32_16x16x32_bf16(a2, b0, acc[2][0], 0, 0, 0);
      acc[2][1] = __builtin_amdgcn_mfma_f32_16x16x32_bf16(a2, b1, acc[2][1], 0, 0, 0);
      acc[2][2] = __builtin_amdgcn_mfma_f32_16x16x32_bf16(a2, b2, acc[2][2], 0, 0, 0);
      acc[2][3] = __builtin_amdgcn_mfma_f32_16x16x32_bf16(a2, b3, acc[2][3], 0, 0, 0);
      acc[3][0] = __builtin_amdgcn_mfma_f32_16x16x32_bf16(a3, b0, acc[3][0], 0, 0, 0);
      acc[3][1] = __builtin_amdgcn_mfma_f32_16x16x32_bf16(a3, b1, acc[3][1], 0, 0, 0);
      acc[3][2] = __builtin_amdgcn_mfma_f32_16x16x32_bf16(a3, b2, acc[3][2], 0, 0, 0);
      acc[3][3] = __builtin_amdgcn_mfma_f32_16x16x32_bf16(a3, b3, acc[3][3], 0, 0, 0);
      __builtin_amdgcn_s_setprio(0);
    }

    // ---- landed-wait + A write + barrier
    if (t + 1 < 16) {
      if (t + 2 < 16) asm volatile("s_waitcnt vmcnt(2)" ::: "memory");
      else            asm volatile("s_waitcnt vmcnt(0)" ::: "memory");
      A_WRITE(areg, (t + 1) & 1);
    }
    if (t + 1 < 16) {
      asm volatile("s_waitcnt lgkmcnt(0)" ::: "memory");
      __builtin_amdgcn_s_barrier();
    }
  }
#undef STG_B
#undef A_ISSUE
#undef A_WRITE

  float scale = (z == 0) ? qscale : 1.0f;
#pragma unroll
  for (int i = 0; i < 4; i++)
#pragma unroll
    for (int j = 0; j < 4; j++) {
      int gc = n0 + wn * 64 + j * 16 + c16;
      float bvv = bias[gc];
      float val[4];
#pragma unroll
      for (int r = 0; r < 4; r++) val[r] = (acc[i][j][r] + bvv) * scale;
      int gr0 = m0 + wm * 64 + i * 16 + quad * 4;
      if (z < 2) {
        unsigned short* O = (z == 0) ? Qb : Kb;
#pragma unroll
        for (int r = 0; r < 4; r++) O[(size_t)(gr0 + r) * DM + gc] = f2bf(val[r]);
      } else {
        // V transposed + kv-permuted: s stored at column c = s with bits 2<->3 swapped
        int hh = gc >> 6, dd = gc & 63;
        int bidx = gr0 >> 11, srow = gr0 & 2047;
        int s6 = srow & 63;   // low 2 bits 0
        int c6 = (s6 & 51) | ((s6 & 4) << 1) | ((s6 & 8) >> 1);
        int srowp = (srow & ~63) | c6;
        uint2 pk;
        pk.x = pack_bf(val[0], val[1]);
        pk.y = pack_bf(val[2], val[3]);
        *(uint2*)&VtOut[((size_t)(bidx * 16 + hh) * 64 + dd) * SQL + srowp] = pk;
      }
    }
}

// ---------------- deep-pipelined GEMM core (bf16 A via GLD): C[256x128], BK=64.
__device__ __forceinline__ void gemm_core_256x128(
    const unsigned short* __restrict__ A, const unsigned short* __restrict__ Bt,
    int m0, int n0, unsigned short* lds_a, unsigned short* lds_b,
    floatx4 acc[4][4]) {
  int tid = threadIdx.x;
  int wave = tid >> 6, lane = tid & 63;
  int quad = lane >> 4, c16 = lane & 15;
  int wm = wave >> 1, wn = wave & 1;
  int r8 = lane >> 3, l8 = lane & 7;
  int xch = (l8 ^ r8) << 3;

  int r7 = c16 & 7;
  int aoff0 = ((wm * 64 + c16) << 6) + ((quad ^ r7) << 3);
  int aoff1 = ((wm * 64 + c16) << 6) + (((4 + quad) ^ r7) << 3);
  int boff0 = ((wn * 64 + c16) << 6) + ((quad ^ r7) << 3);
  int boff1 = ((wn * 64 + c16) << 6) + (((4 + quad) ^ r7) << 3);

  int aq = wave * 4;
  int bq = wave * 2;

#define STG_A(bufp, kt, u) \
  GLD(&A[(size_t)(m0 + (aq + (u)) * 8 + r8) * DM + (kt) + xch], (bufp) + (aq + (u)) * 512)
#define STG_B(bufp, kt, u) \
  GLD(&Bt[(size_t)(n0 + (bq + (u)) * 8 + r8) * DM + (kt) + xch], (bufp) + (bq + (u)) * 512)

  const floatx4 fz = {0.f, 0.f, 0.f, 0.f};
#pragma unroll
  for (int i = 0; i < 4; i++)
#pragma unroll
    for (int j = 0; j < 4; j++) acc[i][j] = fz;

#pragma unroll
  for (int u = 0; u < 4; u++) STG_A(lds_a, 0, u);
  STG_B(lds_b, 0, 0);
  STG_B(lds_b, 0, 1);
#pragma unroll
  for (int u = 0; u < 4; u++) STG_A(lds_a + 16384, 64, u);
  STG_B(lds_b + 8192, 64, 0);
  STG_B(lds_b + 8192, 64, 1);

  int cur = 0;
#pragma unroll 1
  for (int t = 0; t < 16; ++t) {
    if (t < 15) asm volatile("s_waitcnt vmcnt(6)\n\ts_barrier" ::: "memory");
    else        asm volatile("s_waitcnt vmcnt(0)\n\ts_barrier" ::: "memory");

    const unsigned short* la = lds_a + cur * 16384;
    const unsigned short* lb = lds_b + cur * 8192;
    int stg = cur + 2;
    if (stg >= 3) stg -= 3;
    unsigned short* sa = lds_a + stg * 16384;
    unsigned short* sb = lds_b + stg * 8192;
    bool do_st = (t < 14);
    int kt2 = (t + 2) << 6;

    bf16x8 a_[2], b0[4], b1[4];

    a_[0] = *(const bf16x8*)&la[aoff0];
    a_[1] = *(const bf16x8*)&la[aoff0 + 1024];
    b0[0] = *(const bf16x8*)&lb[boff0];
    b0[1] = *(const bf16x8*)&lb[boff0 + 1024];
    b0[2] = *(const bf16x8*)&lb[boff0 + 2048];
    b0[3] = *(const bf16x8*)&lb[boff0 + 3072];
    if (do_st) { STG_A(sa, kt2, 0); STG_A(sa, kt2, 1); }
    __builtin_amdgcn_s_barrier();
    __builtin_amdgcn_s_setprio(1);
#pragma unroll
    for (int j = 0; j < 4; j++)
      acc[0][j] = __builtin_amdgcn_mfma_f32_16x16x32_bf16(a_[0], b0[j], acc[0][j], 0, 0, 0);
#pragma unroll
    for (int j = 0; j < 4; j++)
      acc[1][j] = __builtin_amdgcn_mfma_f32_16x16x32_bf16(a_[1], b0[j], acc[1][j], 0, 0, 0);
    __builtin_amdgcn_s_setprio(0);
    __builtin_amdgcn_s_barrier();

    a_[0] = *(const bf16x8*)&la[aoff0 + 2048];
    a_[1] = *(const bf16x8*)&la[aoff0 + 3072];
    if (do_st) { STG_A(sa, kt2, 2); STG_A(sa, kt2, 3); }
    __builtin_amdgcn_s_barrier();
    __builtin_amdgcn_s_setprio(1);
#pragma unroll
    for (int j = 0; j < 4; j++)
      acc[2][j] = __builtin_amdgcn_mfma_f32_16x16x32_bf16(a_[0], b0[j], acc[2][j], 0, 0, 0);
#pragma unroll
    for (int j = 0; j < 4; j++)
      acc[3][j] = __builtin_amdgcn_mfma_f32_16x16x32_bf16(a_[1], b0[j], acc[3][j], 0, 0, 0);
    __builtin_amdgcn_s_setprio(0);
    __builtin_amdgcn_s_barrier();

    a_[0] = *(const bf16x8*)&la[aoff1];
    a_[1] = *(const bf16x8*)&la[aoff1 + 1024];
    b1[0] = *(const bf16x8*)&lb[boff1];
    b1[1] = *(const bf16x8*)&lb[boff1 + 1024];
    b1[2] = *(const bf16x8*)&lb[boff1 + 2048];
    b1[3] = *(const bf16x8*)&lb[boff1 + 3072];
    if (do_st) { STG_B(sb, kt2, 0); STG_B(sb, kt2, 1); }
    __builtin_amdgcn_s_barrier();
    __builtin_amdgcn_s_setprio(1);
#pragma unroll
    for (int j = 0; j < 4; j++)
      acc[0][j] = __builtin_amdgcn_mfma_f32_16x16x32_bf16(a_[0], b1[j], acc[0][j], 0, 0, 0);
#pragma unroll
    for (int j = 0; j < 4; j++)
      acc[1][j] = __builtin_amdgcn_mfma_f32_16x16x32_bf16(a_[1], b1[j], acc[1][j], 0, 0, 0);
    __builtin_amdgcn_s_setprio(0);
    __builtin_amdgcn_s_barrier();

    a_[0] = *(const bf16x8*)&la[aoff1 + 2048];
    a_[1] = *(const bf16x8*)&la[aoff1 + 3072];
    __builtin_amdgcn_s_barrier();
    __builtin_amdgcn_s_setprio(1);
#pragma unroll
    for (int j = 0; j < 4; j++)
      acc[2][j] = __builtin_amdgcn_mfma_f32_16x16x32_bf16(a_[0], b1[j], acc[2][j], 0, 0, 0);
#pragma unroll
    for (int j = 0; j < 4; j++)
      acc[3][j] = __builtin_amdgcn_mfma_f32_16x16x32_bf16(a_[1], b1[j], acc[3][j], 0, 0, 0);
    __builtin_amdgcn_s_setprio(0);

    cur = cur + 1;
    if (cur >= 3) cur = 0;
  }
#undef STG_A
#undef STG_B
}

// ---------------- output GEMM: out[8192][1024] f32 = Cv_bf16 @ wot^T + bo
__global__ __launch_bounds__(512, 2) void gemm_out_kernel(
    const unsigned short* __restrict__ A, const unsigned short* __restrict__ Bt,
    const float* __restrict__ bias, float* __restrict__ O) {
  __shared__ unsigned short lds_a[3 * 256 * 64];
  __shared__ unsigned short lds_b[3 * 128 * 64];

  int lin = blockIdx.x + (blockIdx.y << 3);
  int swz = (lin & 7) * 32 + (lin >> 3);
  int m0 = (swz >> 3) << 8;
  int n0 = (swz & 7) << 7;

  floatx4 acc[4][4];
  gemm_core_256x128(A, Bt, m0, n0, lds_a, lds_b, acc);

  int tid = threadIdx.x;
  int wave = tid >> 6, lane = tid & 63;
  int quad = lane >> 4, c16 = lane & 15;
  int wm = wave >> 1, wn = wave & 1;

#pragma unroll
  for (int i = 0; i < 4; i++)
#pragma unroll
    for (int j = 0; j < 4; j++) {
      int gc = n0 + wn * 64 + j * 16 + c16;
      float bvv = bias[gc];
      int gr0 = m0 + wm * 64 + i * 16 + quad * 4;
#pragma unroll
      for (int r = 0; r < 4; r++) O[(size_t)(gr0 + r) * DM + gc] = acc[i][j][r] + bvv;
    }
}

// ---------------- flash attention (best-measured, 83.6us), 32x32x16 MFMA.
// Per wave: 32 q rows (q = lane&31, hl = lane>>5 selects d/kv half).
// QK: S^T[kv][q] = mfma(A=K-rows, B=Q^T); C: col=q (lane&31), kv=(reg&3)+8*(reg>>2)+4hl.
// PV: O^T[d][q] = mfma(A=Vt-rows, B=P^T); V stored with kv bits 2<->3 swapped so
// QK C-regs ARE the PV B-fragment in identity order.
// Staging: 4 global_load_lds per wave per tile into the inactive buffer,
// pre-swizzled source slot (lane&7)^(lane>>3); one __syncthreads per tile.
__global__ __launch_bounds__(256, 3) void attn_kernel(
    const unsigned short* __restrict__ Qb, const unsigned short* __restrict__ Kb,
    const unsigned short* __restrict__ Vt, unsigned short* __restrict__ Cv) {
  __shared__ unsigned short lds_k[2][64 * 64];   // [kv][d] swizzled
  __shared__ unsigned short lds_v[2][64 * 64];   // [d][kv-permuted] swizzled
  int tid = threadIdx.x;
  int wave = tid >> 6, lane = tid & 63;
  int q31 = lane & 31, hl = lane >> 5;
  int bh = blockIdx.x, qt = blockIdx.y;
  int b = bh >> 4, h = bh & 15;

  int rl = lane >> 3;                       // row within 8-row group
  int xsl = ((lane & 7) ^ rl) << 3;         // pre-swizzled slot offset (halves)
  const unsigned short* kg = &Kb[(size_t)(b * SQL + wave * 16 + rl) * DM + h * 64 + xsl];
  const unsigned short* vg = &Vt[((size_t)(bh * 64) + wave * 16 + rl) * SQL + xsl];

  bf16x8 qf[4];
  int gr = b * SQL + qt * 128 + wave * 32 + q31;
#pragma unroll
  for (int s = 0; s < 4; s++)
    qf[s] = *(const bf16x8*)&Qb[(size_t)gr * DM + h * 64 + s * 16 + hl * 8];

  const floatx16 fz16 = {0.f, 0.f, 0.f, 0.f, 0.f, 0.f, 0.f, 0.f,
                         0.f, 0.f, 0.f, 0.f, 0.f, 0.f, 0.f, 0.f};
  floatx16 o[2];
  o[0] = fz16; o[1] = fz16;
  float l_ = 0.f;

#pragma unroll
  for (int u = 0; u < 2; u++) {
    GLD(kg + (size_t)(u * 8) * DM, &lds_k[0][(wave * 16 + u * 8) << 6]);
    GLD(vg + (size_t)(u * 8) * SQL, &lds_v[0][(wave * 16 + u * 8) << 6]);
  }
  __syncthreads();

#pragma unroll 1
  for (int t = 0; t < 32; t++) {
    int cur = t & 1, nxt = cur ^ 1;
    if (t + 1 < 32) {
      size_t koff = (size_t)((t + 1) * 64) * DM;
      size_t voff = (size_t)((t + 1) * 64);
#pragma unroll
      for (int u = 0; u < 2; u++) {
        GLD(kg + koff + (size_t)(u * 8) * DM, &lds_k[nxt][(wave * 16 + u * 8) << 6]);
        GLD(vg + voff + (size_t)(u * 8) * SQL, &lds_v[nxt][(wave * 16 + u * 8) << 6]);
      }
    }

    floatx16 st[2];
    __builtin_amdgcn_s_setprio(1);
#pragma unroll
    for (int j = 0; j < 2; j++) {
      bf16x8 kf = *(const bf16x8*)&lds_k[cur][SW(j * 32 + q31, hl)];
      st[j] = __builtin_amdgcn_mfma_f32_32x32x16_bf16(kf, qf[0], fz16, 0, 0, 0);
    }
#pragma unroll
    for (int s = 1; s < 4; s++)
#pragma unroll
      for (int j = 0; j < 2; j++) {
        bf16x8 kf = *(const bf16x8*)&lds_k[cur][SW(j * 32 + q31, 2 * s + hl)];
        st[j] = __builtin_amdgcn_mfma_f32_32x32x16_bf16(kf, qf[s], st[j], 0, 0, 0);
      }
    __builtin_amdgcn_s_setprio(0);

#pragma unroll
    for (int j = 0; j < 2; j++)
#pragma unroll
      for (int r = 0; r < 16; r++) st[j][r] = __builtin_amdgcn_exp2f(st[j][r]);
    float p0 = 0.f, p1 = 0.f, p2 = 0.f, p3 = 0.f;
#pragma unroll
    for (int r = 0; r < 16; r += 2) {
      p0 += st[0][r]; p1 += st[0][r + 1];
      p2 += st[1][r]; p3 += st[1][r + 1];
    }
    l_ += (p0 + p1) + (p2 + p3);

    bf16x8 pb[2][2];
#pragma unroll
    for (int j = 0; j < 2; j++)
#pragma unroll
      for (int s2 = 0; s2 < 2; s2++) {
        bf16x8 r;
#pragma unroll
        for (int e = 0; e < 8; e++) r[e] = (__bf16)st[j][s2 * 8 + e];
        pb[j][s2] = r;
      }

    __builtin_amdgcn_s_setprio(1);
#pragma unroll
    for (int dt = 0; dt < 2; dt++)
#pragma unroll
      for (int j = 0; j < 2; j++)
#pragma unroll
        for (int s2 = 0; s2 < 2; s2++) {
          bf16x8 av = *(const bf16x8*)&lds_v[cur][SW(dt * 32 + q31, j * 4 + s2 * 2 + hl)];
          o[dt] = __builtin_amdgcn_mfma_f32_32x32x16_bf16(av, pb[j][s2], o[dt], 0, 0, 0);
        }
    __builtin_amdgcn_s_setprio(0);

    __syncthreads();
  }

  l_ += __shfl_xor(l_, 32);
  float inv = 1.f / l_;
#pragma unroll
  for (int dt = 0; dt < 2; dt++)
#pragma unroll
    for (int g = 0; g < 4; g++) {
      bf16x4 ov;
      ov[0] = (__bf16)(o[dt][4 * g + 0] * inv);
      ov[1] = (__bf16)(o[dt][4 * g + 1] * inv);
      ov[2] = (__bf16)(o[dt][4 * g + 2] * inv);
      ov[3] = (__bf16)(o[dt][4 * g + 3] * inv);
      int d0 = dt * 32 + g * 8 + hl * 4;
      *(bf16x4*)&Cv[(size_t)gr * DM + h * 64 + d0] = ov;
    }
}

extern "C" void kernel_launch(void* const* d_in, const int* in_sizes, int n_in,
                              void* d_out, int out_size, void* d_ws, size_t ws_size,
                              hipStream_t stream) {
  const float* q  = (const float*)d_in[0];
  const float* k  = (const float*)d_in[1];
  const float* v  = (const float*)d_in[2];
  const float* wq = (const float*)d_in[3];
  const float* bq = (const float*)d_in[4];
  const float* wk = (const float*)d_in[5];
  const float* bk = (const float*)d_in[6];
  const float* wv = (const float*)d_in[7];
  const float* bv = (const float*)d_in[8];
  const float* wo = (const float*)d_in[9];
  const float* bo = (const float*)d_in[10];
  float* out = (float*)d_out;

  char* ws = (char*)d_ws;
  unsigned short* wqt = (unsigned short*)(ws + (size_t)0);
  unsigned short* wkt = (unsigned short*)(ws + ((size_t)2 << 20));
  unsigned short* wvt = (unsigned short*)(ws + ((size_t)4 << 20));
  unsigned short* wot = (unsigned short*)(ws + ((size_t)6 << 20));
  unsigned short* Qb  = (unsigned short*)(ws + ((size_t)8 << 20));
  unsigned short* Kb  = (unsigned short*)(ws + ((size_t)24 << 20));
  unsigned short* Vt  = (unsigned short*)(ws + ((size_t)40 << 20));
  unsigned short* Cv  = (unsigned short*)(ws + ((size_t)56 << 20));

  const float QSCALE = 0.125f * 1.44269504088896340736f;  // 1/sqrt(64) * log2(e)

  dim3 blk(256);
  transpose4_kernel<<<dim3(16, 16, 4), blk, 0, stream>>>(wq, wk, wv, wo, wqt, wkt, wvt, wot);
  gemm_qkv_kernel<<<dim3(8, 32, 3), dim3(512), 0, stream>>>(q, k, v, wqt, wkt, wvt,
                                                            bq, bk, bv, Qb, Kb, Vt, QSCALE);
  attn_kernel<<<dim3(64, 16), blk, 0, stream>>>(Qb, Kb, Vt, Cv);
  gemm_out_kernel<<<dim3(8, 32), dim3(512), 0, stream>>>(Cv, wot, bo, out);
}